// Round 13
// baseline (802.029 us; speedup 1.0000x reference)
//
#include <hip/hip_runtime.h>
#include <hip/hip_bf16.h>
#include <math.h>

// Problem dims
#define BB 32
#define TE 80
#define FEAT 4096
#define HH 256
#define W2V 256
#define TD 30
#define VV 32000
#define G4 1024   // 4*H

typedef unsigned short u16;
typedef unsigned int u32;
using f32x4 = __attribute__((ext_vector_type(4))) float;
using bf16x8 = __attribute__((ext_vector_type(8))) short;
using f16x2 = __attribute__((ext_vector_type(2))) _Float16;

#define SENT 0xFFFFFFFFu
#define GUARD (1 << 22)

__device__ __forceinline__ float sigm(float x) { return 1.0f / (1.0f + expf(-x)); }
__device__ __forceinline__ u16 f2bf(float f) {
  u32 u = __float_as_uint(f);
  u32 r = (u + 0x7FFFu + ((u >> 16) & 1u)) >> 16;
  return (u16)r;
}
__device__ __forceinline__ u32 packh2(float lo, float hi) {
  f16x2 v = {(_Float16)lo, (_Float16)hi};
  return __builtin_bit_cast(u32, v);
}
__device__ __forceinline__ u32 packbf2(float lo, float hi) {
  return (u32)f2bf(lo) | ((u32)f2bf(hi) << 16);
}

#define AT_LOAD(p)     __hip_atomic_load((p), __ATOMIC_RELAXED, __HIP_MEMORY_SCOPE_AGENT)
#define AT_STORE(p, v) __hip_atomic_store((p), (v), __ATOMIC_RELAXED, __HIP_MEMORY_SCOPE_AGENT)
#define AT_ADD(p, v)   __hip_atomic_fetch_add((p), (v), __ATOMIC_RELAXED, __HIP_MEMORY_SCOPE_AGENT)

__device__ __forceinline__ float fdot2h(f16x2 a, f16x2 b, float c) {
#if __has_builtin(__builtin_amdgcn_fdot2)
  return __builtin_amdgcn_fdot2(a, b, c, false);
#else
  return c + (float)a[0] * (float)b[0] + (float)a[1] * (float)b[1];
#endif
}

// ctrs indices
#define C_BAR 0
#define C_WRT 32
#define C_ARGQ 64
#define C_ARGD 72
#define C_CHQ 96
#define C_RG 128   // +rg (29)

// ===========================================================================
// prep: w_ih1->bf16 | H1H/H2H sentinels | A2P sentinels | bias/ctrs/loss
// blocks: [0,1024) | [1024,1464) | [1464,1904) | 1904   => 1905
// ===========================================================================
__global__ __launch_bounds__(256) void prep_kernel(
    const float* __restrict__ w_ih1,
    const float* __restrict__ b_ih1, const float* __restrict__ b_hh1,
    const float* __restrict__ b_ih2, const float* __restrict__ b_hh2,
    u16* __restrict__ w_ih1b,
    float* __restrict__ bias1, float* __restrict__ bias2,
    u32* __restrict__ H1H, u32* __restrict__ H2H, u32* __restrict__ A2P,
    float* __restrict__ loss, int* __restrict__ ctrs) {
  int blk = blockIdx.x, tid = threadIdx.x;
  if (blk < 1024) {
    int i0 = blk * 1024 + tid;
#pragma unroll
    for (int ii = 0; ii < 4; ++ii) {
      int i = i0 + ii * 256;
      float4 v = *(const float4*)&w_ih1[(size_t)i * 4];
      *(ushort4*)&w_ih1b[(size_t)i * 4] =
          make_ushort4(f2bf(v.x), f2bf(v.y), f2bf(v.z), f2bf(v.w));
    }
  } else if (blk < 1464) {
    int i = (blk - 1024) * 256 + tid;  // uint4 idx < 112640
    uint4 z = {0u, 0u, 0u, 0u};
    uint4 s = {SENT, SENT, SENT, SENT};
    uint4 v = (i < 1024) ? z : s;      // slot T=0 = packed f16 zeros
    ((uint4*)H1H)[i] = v;
    ((uint4*)H2H)[i] = v;
  } else if (blk < 1904) {
    int i0 = (blk - 1464) * 1024 + tid;  // uint4 idx < 450560
    uint4 s = {SENT, SENT, SENT, SENT};
#pragma unroll
    for (int ii = 0; ii < 4; ++ii) ((uint4*)A2P)[i0 + ii * 256] = s;
  } else {
    for (int i = tid; i < 1024; i += 256) {
      bias1[i] = b_ih1[i] + b_hh1[i];
      bias2[i] = b_ih2[i] + b_hh2[i];
    }
    if (tid < 256) ctrs[tid] = 0;
    if (tid == 0) *loss = 0.0f;
  }
}

// ===========================================================================
// Params for the mega-kernel
// ===========================================================================
struct RP {
  const float *feat, *caption, *onehot;
  const float *w_hh1, *w_ih2, *w_hh2, *w_out, *b_out;
  const float *bias1, *bias2;
  const u16* w_ih1b;
  u32* H1H;     // [110][32][128] packed f16x2 of h1[T]
  u32* H2H;     // [110][32][128] packed f16x2 of h2[U]
  u32* A2P;     // [110][32][512] packed f16x2 pairs of a2 rows
  u32* H2NB32;  // [29][32][128] packed bf16x2 of decoder h2n
  u32 *pmaxA, *psumA, *tgtv;  // [928][2000], [928][2000], [928]
  float* loss;
  int* ctrs;
  int* targets;
  float* out;
};

// ---------------------------------------------------------------------------
// Fused logits+CE-partials worker: claims 128-col chunks, processes 29 rgs
// as they become ready (rgctr). 8 waves, 1 n-tile each.
// ---------------------------------------------------------------------------
__device__ void do_logits(char* smem, const RP& p) {
  u16* bS = (u16*)smem;              // 65536
  u16* aS = (u16*)(smem + 65536);    // [32][264] u16
  int* tS = (int*)(smem + 82432);    // 32 ints
  int* chS = (int*)(smem + 82560);
  int tid = threadIdx.x;
  if (tid == 0) {  // wait for all argmax targets
    int gd = 0;
    while (AT_LOAD(&p.ctrs[C_ARGD]) < 928 && ++gd < GUARD) __builtin_amdgcn_s_sleep(2);
  }
  __syncthreads();
  int w = tid >> 6, lane = tid & 63, lcol = lane & 15, lk = lane >> 4;
  while (true) {
    if (tid == 0) *chS = AT_ADD(&p.ctrs[C_CHQ], 1);
    __syncthreads();
    int ch = *chS;
    if (ch >= 250) break;
    // stage B: cols [ch*128, +128), f32 -> bf16 MFMA layout
#pragma unroll
    for (int it = 0; it < 8; ++it) {
      int id = it * 512 + tid;  // < 4096 : nt*512 + rr*32 + kg
      int nt = id >> 9, rr = (id >> 5) & 15, kg = id & 31;
      int n = ch * 128 + nt * 16 + rr;
      const float* src = &p.w_out[(size_t)n * 256 + kg * 8];
      float4 v0 = *(const float4*)src;
      float4 v1 = *(const float4*)(src + 4);
      u16* dst = &bS[(size_t)((nt * 32 + kg) * 16 + rr) * 8];
      *(ushort4*)dst = make_ushort4(f2bf(v0.x), f2bf(v0.y), f2bf(v0.z), f2bf(v0.w));
      *(ushort4*)(dst + 4) = make_ushort4(f2bf(v1.x), f2bf(v1.y), f2bf(v1.z), f2bf(v1.w));
    }
    float bo = p.b_out[ch * 128 + w * 16 + lcol];
    for (int rg = 0; rg < 29; ++rg) {
      if (tid == 0) {
        int gd = 0;
        while (AT_LOAD(&p.ctrs[C_RG + rg]) < 128 && ++gd < GUARD) __builtin_amdgcn_s_sleep(1);
      }
      __syncthreads();
      // stage A (H2NB rowgroup) via agent loads
#pragma unroll
      for (int it = 0; it < 8; ++it) {
        int i = it * 512 + tid;  // < 4096 u32
        int r = i >> 7, cu = i & 127;
        u32 v = AT_LOAD(&p.H2NB32[((size_t)rg * 32 + r) * 128 + cu]);
        aS[r * 264 + cu * 2] = (u16)(v & 0xFFFF);
        aS[r * 264 + cu * 2 + 1] = (u16)(v >> 16);
      }
      if (tid < 32) tS[tid] = AT_LOAD(&p.targets[rg * 32 + tid]);
      __syncthreads();
      f32x4 acc[2];
      acc[0] = (f32x4){0.f, 0.f, 0.f, 0.f};
      acc[1] = (f32x4){0.f, 0.f, 0.f, 0.f};
#pragma unroll
      for (int ks = 0; ks < 8; ++ks) {
        bf16x8 bfr = *(const bf16x8*)&bS[(size_t)((w * 32 + ks * 4 + lk) * 16 + lcol) * 8];
        bf16x8 a0 = *(const bf16x8*)&aS[lcol * 264 + ks * 32 + lk * 8];
        bf16x8 a1 = *(const bf16x8*)&aS[(16 + lcol) * 264 + ks * 32 + lk * 8];
        acc[0] = __builtin_amdgcn_mfma_f32_16x16x32_bf16(a0, bfr, acc[0], 0, 0, 0);
        acc[1] = __builtin_amdgcn_mfma_f32_16x16x32_bf16(a1, bfr, acc[1], 0, 0, 0);
      }
      int ncol = ch * 128 + w * 16 + lcol;
      int chunkW = ch * 8 + w;
#pragma unroll
      for (int m = 0; m < 2; ++m) {
        float pm[4], psv[4];
#pragma unroll
        for (int qq = 0; qq < 4; ++qq) {
          float v0 = acc[m][qq] + bo;
          int r = m * 16 + lk * 4 + qq;
          if (tS[r] == ncol) AT_STORE(&p.tgtv[rg * 32 + r], __float_as_uint(v0));
          float mx = v0;
#pragma unroll
          for (int d = 1; d < 16; d <<= 1) mx = fmaxf(mx, __shfl_xor(mx, d));
          float e = expf(v0 - mx);
#pragma unroll
          for (int d = 1; d < 16; d <<= 1) e += __shfl_xor(e, d);
          pm[qq] = mx;
          psv[qq] = e;
        }
        if (lcol == 0) {
#pragma unroll
          for (int qq = 0; qq < 4; ++qq) {
            int r2 = (rg * 32 + m * 16 + lk * 4 + qq);
            AT_STORE(&p.pmaxA[(size_t)r2 * 2000 + chunkW], __float_as_uint(pm[qq]));
            AT_STORE(&p.psumA[(size_t)r2 * 2000 + chunkW], __float_as_uint(psv[qq]));
          }
        }
      }
      __syncthreads();
    }
  }
}

// ===========================================================================
// Mega cooperative kernel: 256 blocks x 512 threads.
// ===========================================================================
__global__ __launch_bounds__(512, 1) void mega_kernel(RP p) {
  __shared__ __align__(16) char smem[133120];
  int bid = blockIdx.x, tid = threadIdx.x;
  bool isL1 = bid < 128;
  int lb = isL1 ? bid : bid - 128;
  int b = lb >> 2, q = lb & 3;
  int r2 = tid >> 1, half = tid & 1;
  int g = r2 >> 6, jj = r2 & 63;
  int grow = (g << 8) + (q << 6) + jj;

  if (isL1) {
    u16* As = (u16*)smem;                    // [80][72]
    u16* Bs = (u16*)(smem + 11520);          // [256][72]
    float* X1L = (float*)(smem + 48384);     // [80][257]
    f16x2* hS = (f16x2*)(smem + 130624);
    float* gb = (float*)(smem + 131136);
    float* hnew = (float*)(smem + 132160);
    // ---------- prologue: X1 slice via MFMA (feat f32 inline) ----------
    {
      int lane = tid & 63, w = tid >> 6;
      int lrow = lane & 15, lk = (lane >> 4) * 8;
      f32x4 acc[5][2];
#pragma unroll
      for (int m = 0; m < 5; ++m)
#pragma unroll
        for (int n = 0; n < 2; ++n) acc[m][n] = (f32x4){0.f, 0.f, 0.f, 0.f};
      for (int k0 = 0; k0 < FEAT; k0 += 64) {
        for (int f = tid; f < 1280; f += 512) {
          int r = f >> 4, c4 = f & 15;
          float4 v = *(const float4*)&p.feat[((size_t)(b * 80 + r)) * FEAT + k0 + c4 * 4];
          *(ushort4*)&As[r * 72 + c4 * 4] =
              make_ushort4(f2bf(v.x), f2bf(v.y), f2bf(v.z), f2bf(v.w));
        }
#pragma unroll
        for (int it = 0; it < 4; ++it) {
          int f = it * 512 + tid;
          int r = f >> 3, c8 = f & 7;
          int gg = r >> 6, u = r & 63;
          *(uint4*)&Bs[r * 72 + c8 * 8] =
              *(const uint4*)&p.w_ih1b[((size_t)(gg * 256 + q * 64 + u)) * FEAT + k0 + c8 * 8];
        }
        __syncthreads();
#pragma unroll
        for (int ks = 0; ks < 2; ++ks) {
          bf16x8 bfr[2];
#pragma unroll
          for (int n = 0; n < 2; ++n)
            bfr[n] = *(const bf16x8*)&Bs[((w * 2 + n) * 16 + lrow) * 72 + ks * 32 + lk];
#pragma unroll
          for (int m = 0; m < 5; ++m) {
            bf16x8 af = *(const bf16x8*)&As[(m * 16 + lrow) * 72 + ks * 32 + lk];
#pragma unroll
            for (int n = 0; n < 2; ++n)
              acc[m][n] = __builtin_amdgcn_mfma_f32_16x16x32_bf16(af, bfr[n], acc[m][n], 0, 0, 0);
          }
        }
        __syncthreads();
      }
      int lcol = lane & 15, orow = (lane >> 4) * 4;
#pragma unroll
      for (int m = 0; m < 5; ++m)
#pragma unroll
        for (int n = 0; n < 2; ++n) {
          int cn = (w * 2 + n) * 16 + lcol;
          int gc = (cn >> 6) * 256 + q * 64 + (cn & 63);
          float bv = p.bias1[gc];
#pragma unroll
          for (int qq = 0; qq < 4; ++qq)
            X1L[(m * 16 + orow + qq) * 257 + cn] = acc[m][n][qq] + bv;
        }
      __syncthreads();
    }
    // ---------- chain ----------
    f16x2 wA[64], wB[64];
    {
      const float4* sA = (const float4*)(p.w_hh1 + (size_t)grow * 256 + half * 128);
      const float4* sB = (const float4*)(p.w_ih2 + (size_t)grow * 512 + 256 + half * 128);
#pragma unroll
      for (int k = 0; k < 32; ++k) {
        float4 v = sA[k];
        wA[k * 2 + 0] = f16x2{(_Float16)v.x, (_Float16)v.y};
        wA[k * 2 + 1] = f16x2{(_Float16)v.z, (_Float16)v.w};
        float4 u = sB[k];
        wB[k * 2 + 0] = f16x2{(_Float16)u.x, (_Float16)u.y};
        wB[k * 2 + 1] = f16x2{(_Float16)u.z, (_Float16)u.w};
      }
    }
    float c1 = 0.f;
    float b1v0 = 0, b1v1 = 0, b1v2 = 0, b1v3 = 0;
    if (tid < 64) {
      b1v0 = p.bias1[(q << 6) + tid];
      b1v1 = p.bias1[256 + (q << 6) + tid];
      b1v2 = p.bias1[512 + (q << 6) + tid];
      b1v3 = p.bias1[768 + (q << 6) + tid];
    }
    for (int T = 0; T <= 109; ++T) {
      float x0 = b1v0, x1 = b1v1, x2 = b1v2, x3 = b1v3;
      if (tid < 64 && T < TE) {
        x0 = X1L[T * 257 + tid];
        x1 = X1L[T * 257 + 64 + tid];
        x2 = X1L[T * 257 + 128 + tid];
        x3 = X1L[T * 257 + 192 + tid];
      }
      if (tid < 128) {
        const u32* src = &p.H1H[((size_t)T * 32 + b) * 128 + tid];
        u32 v = AT_LOAD(src);
        int gd = 0;
        while (v == SENT && ++gd < GUARD) {
          __builtin_amdgcn_s_sleep(1);
          v = AT_LOAD(src);
        }
        hS[tid] = __builtin_bit_cast(f16x2, v);
      }
      __syncthreads();
      float a1 = 0.f, a2 = 0.f;
      {
        const uint4* hv = ((const uint4*)hS) + half * 16;
#pragma unroll
        for (int k = 0; k < 16; ++k) {
          uint4 uu = hv[k];
          f16x2 e0 = __builtin_bit_cast(f16x2, uu.x), e1 = __builtin_bit_cast(f16x2, uu.y);
          f16x2 e2 = __builtin_bit_cast(f16x2, uu.z), e3 = __builtin_bit_cast(f16x2, uu.w);
          a1 = fdot2h(e0, wA[k * 4 + 0], a1);
          a2 = fdot2h(e0, wB[k * 4 + 0], a2);
          a1 = fdot2h(e1, wA[k * 4 + 1], a1);
          a2 = fdot2h(e1, wB[k * 4 + 1], a2);
          a1 = fdot2h(e2, wA[k * 4 + 2], a1);
          a2 = fdot2h(e2, wB[k * 4 + 2], a2);
          a1 = fdot2h(e3, wA[k * 4 + 3], a1);
          a2 = fdot2h(e3, wB[k * 4 + 3], a2);
        }
      }
      a1 += __shfl_xor(a1, 1);
      a2 += __shfl_xor(a2, 1);
      float a2o = __shfl_xor(a2, 2);  // partner row's a2
      if (half == 0) gb[r2] = a1;
      if ((tid & 3) == 0 && T >= 1) {
        int pr = tid >> 2;  // local pair = (g<<5)+(jj>>1)
        int gp = pr >> 5, wp = pr & 31;
        AT_STORE(&p.A2P[((size_t)T * 32 + b) * 512 + (gp << 7) + (q << 5) + wp],
                 packh2(a2, a2o));
      }
      __syncthreads();
      if (T <= 108) {
        if (tid < 64) {
          float gi = gb[tid] + x0;
          float gf = gb[64 + tid] + x1;
          float gG = gb[128 + tid] + x2;
          float go = gb[192 + tid] + x3;
          c1 = sigm(gf) * c1 + sigm(gi) * tanhf(gG);
          hnew[tid] = sigm(go) * tanhf(c1);
        }
        if (tid < 32) {
          u32 pk = packh2(hnew[2 * tid], hnew[2 * tid + 1]);
          AT_STORE(&p.H1H[((size_t)(T + 1) * 32 + b) * 128 + (q << 5) + tid], pk);
        }
      }
    }
    // ---------- post-chain: argmax queue ----------
    {
      float* sv = (float*)smem;
      int* si = (int*)(smem + 2048);
      int* jobS = (int*)(smem + 4096);
      __syncthreads();
      while (true) {
        if (tid == 0) *jobS = AT_ADD(&p.ctrs[C_ARGQ], 1);
        __syncthreads();
        int job = *jobS;
        if (job >= 928) break;
        int s = (job >> 5) + 1, bb = job & 31;
        const float* row = &p.onehot[((size_t)bb * TD + s) * VV];
        float bv = -INFINITY;
        int bi = 0x7fffffff;
        for (int v = tid; v < VV; v += 512) {
          float x = row[v];
          if (x > bv || (x == bv && v < bi)) { bv = x; bi = v; }
        }
        sv[tid] = bv;
        si[tid] = bi;
        __syncthreads();
        for (int off = 256; off; off >>= 1) {
          if (tid < off) {
            float ov = sv[tid + off];
            int oi = si[tid + off];
            if (ov > sv[tid] || (ov == sv[tid] && oi < si[tid])) { sv[tid] = ov; si[tid] = oi; }
          }
          __syncthreads();
        }
        if (tid == 0) {
          AT_STORE(&p.targets[job], si[0]);
          asm volatile("s_waitcnt vmcnt(0)" ::: "memory");
          AT_ADD(&p.ctrs[C_ARGD], 1);
        }
        __syncthreads();
      }
    }
    do_logits(smem, p);
  } else {
    // =============== L2B role ===============
    f16x2* encLh = (f16x2*)smem;             // [80][132]
    u16* g2Lh = (u16*)(smem + 42240);        // [80][264]
    float* XW2L = (float*)(smem + 84480);    // [29][264]
    f16x2* hS = (f16x2*)(smem + 115136);
    float* a2pS = (float*)(smem + 115648);
    float* gb = (float*)(smem + 116672);
    float* hnew = (float*)(smem + 117696);
    float* ps = (float*)(smem + 117952);
    float* sc = (float*)(smem + 119232);
    float* red = (float*)(smem + 119552);
    // ---------- prologue: XW2L (29x256, K=256) in-LDS via MFMA ----------
    {
      u16* pAs = (u16*)smem;                 // [32][264]
      u16* pBs = (u16*)(smem + 16896);       // [64][264]
      for (int f = tid; f < 2048; f += 512) {
        int r = f >> 6, c = f & 63;
        ushort4 o = make_ushort4(0, 0, 0, 0);
        if (r < 29) {
          float4 v = *(const float4*)&p.caption[((size_t)b * TD + r) * 256 + c * 4];
          o = make_ushort4(f2bf(v.x), f2bf(v.y), f2bf(v.z), f2bf(v.w));
        }
        *(ushort4*)&pAs[r * 264 + c * 4] = o;
      }
      int lane = tid & 63, w = tid >> 6;
      int m = w >> 2, n = w & 3;
      int lrow = lane & 15, lk = (lane >> 4) * 8;
      for (int g2 = 0; g2 < 4; ++g2) {
#pragma unroll
        for (int it = 0; it < 8; ++it) {
          int f = it * 512 + tid;  // < 4096
          int r = f >> 6, c = f & 63;
          float4 v = *(const float4*)&p.w_ih2[((size_t)(g2 * 256 + q * 64 + r)) * 512 + c * 4];
          *(ushort4*)&pBs[r * 264 + c * 4] =
              make_ushort4(f2bf(v.x), f2bf(v.y), f2bf(v.z), f2bf(v.w));
        }
        __syncthreads();
        f32x4 acc = (f32x4){0.f, 0.f, 0.f, 0.f};
#pragma unroll
        for (int ks = 0; ks < 8; ++ks) {
          bf16x8 af = *(const bf16x8*)&pAs[(m * 16 + lrow) * 264 + ks * 32 + lk];
          bf16x8 bfr = *(const bf16x8*)&pBs[(n * 16 + lrow) * 264 + ks * 32 + lk];
          acc = __builtin_amdgcn_mfma_f32_16x16x32_bf16(af, bfr, acc, 0, 0, 0);
        }
        int lcol = lane & 15, orow = (lane >> 4) * 4;
        int u = n * 16 + lcol;
        float bv = p.bias2[g2 * 256 + q * 64 + u];
#pragma unroll
        for (int qq = 0; qq < 4; ++qq) {
          int s = m * 16 + orow + qq;
          if (s < 29) XW2L[s * 264 + g2 * 64 + u] = acc[qq] + bv;
        }
        __syncthreads();
      }
    }
    // ---------- chain ----------
    f16x2 wC[64];
    {
      const float4* sC = (const float4*)(p.w_hh2 + (size_t)grow * 256 + half * 128);
#pragma unroll
      for (int k = 0; k < 32; ++k) {
        float4 u = sC[k];
        wC[k * 2 + 0] = f16x2{(_Float16)u.x, (_Float16)u.y};
        wC[k * 2 + 1] = f16x2{(_Float16)u.z, (_Float16)u.w};
      }
    }
    float c2 = 0.f;
    float b2v0 = 0, b2v1 = 0, b2v2 = 0, b2v3 = 0;
    if (tid < 64) {
      b2v0 = p.bias2[(q << 6) + tid];
      b2v1 = p.bias2[256 + (q << 6) + tid];
      b2v2 = p.bias2[512 + (q << 6) + tid];
      b2v3 = p.bias2[768 + (q << 6) + tid];
    }
    for (int U = 1; U <= 109; ++U) {
      float x0 = b2v0, x1 = b2v1, x2 = b2v2, x3 = b2v3;
      if (tid < 64 && U >= 81) {
        int s = U - 81;
        x0 = XW2L[s * 264 + tid];
        x1 = XW2L[s * 264 + 64 + tid];
        x2 = XW2L[s * 264 + 128 + tid];
        x3 = XW2L[s * 264 + 192 + tid];
      }
      if (tid < 128) {
        const u32* src = &p.H2H[((size_t)(U - 1) * 32 + b) * 128 + tid];
        u32 v = AT_LOAD(src);
        int gd = 0;
        while (v == SENT && ++gd < (GUARD << 2)) v = AT_LOAD(src);  // pure spin
        f16x2 hp = __builtin_bit_cast(f16x2, v);
        hS[tid] = hp;
        if (U >= 2 && U <= 81) encLh[(U - 2) * 132 + tid] = hp;
      } else if (tid < 256) {
        int rr = tid - 128;
        int gp = rr >> 5, wp = rr & 31;
        const u32* src = &p.A2P[((size_t)U * 32 + b) * 512 + (gp << 7) + (q << 5) + wp];
        u32 v = AT_LOAD(src);
        int gd = 0;
        while (v == SENT && ++gd < GUARD) {
          __builtin_amdgcn_s_sleep(1);
          v = AT_LOAD(src);
        }
        f16x2 pr = __builtin_bit_cast(f16x2, v);
        a2pS[gp * 64 + 2 * wp] = (float)pr[0];
        a2pS[gp * 64 + 2 * wp + 1] = (float)pr[1];
      }
      __syncthreads();
      float a2p0 = 0, a2p1 = 0, a2p2 = 0, a2p3 = 0;
      if (tid < 64) {
        a2p0 = a2pS[tid];
        a2p1 = a2pS[64 + tid];
        a2p2 = a2pS[128 + tid];
        a2p3 = a2pS[192 + tid];
      }
      if (U <= 81) {
        float a2 = 0.f;
        const uint4* hv = ((const uint4*)hS) + half * 16;
#pragma unroll
        for (int k = 0; k < 16; ++k) {
          uint4 uu = hv[k];
          a2 = fdot2h(__builtin_bit_cast(f16x2, uu.x), wC[k * 4 + 0], a2);
          a2 = fdot2h(__builtin_bit_cast(f16x2, uu.y), wC[k * 4 + 1], a2);
          a2 = fdot2h(__builtin_bit_cast(f16x2, uu.z), wC[k * 4 + 2], a2);
          a2 = fdot2h(__builtin_bit_cast(f16x2, uu.w), wC[k * 4 + 3], a2);
        }
        a2 += __shfl_xor(a2, 1);
        if (half == 0) {
          gb[r2] = a2;
          if (U >= 2) g2Lh[(U - 2) * 264 + r2] = __builtin_bit_cast(u16, (_Float16)a2);
        }
        __syncthreads();
      } else {
        // decoder: scores from encLh vs hS, softmax, combine saved g2
        if (tid < 320) {
          int t = tid >> 2, kq = tid & 3;
          float a = 0.f;
          const f16x2* e = &encLh[t * 132];
#pragma unroll
          for (int i = 0; i < 32; ++i) a = fdot2h(e[kq + 4 * i], hS[kq + 4 * i], a);
          ps[tid] = a;
        }
        __syncthreads();
        float sco = 0.f;
        if (tid < TE) sco = ps[4 * tid] + ps[4 * tid + 1] + ps[4 * tid + 2] + ps[4 * tid + 3];
        float av = (tid < TE) ? sco : -INFINITY;
#pragma unroll
        for (int d = 32; d; d >>= 1) av = fmaxf(av, __shfl_xor(av, d));
        if (tid == 0) red[0] = av;
        if (tid == 64) red[1] = av;
        __syncthreads();
        float m = fmaxf(red[0], red[1]);
        float e2 = (tid < TE) ? expf(sco - m) : 0.f;
        float sv = e2;
#pragma unroll
        for (int d = 32; d; d >>= 1) sv += __shfl_xor(sv, d);
        if (tid == 0) red[2] = sv;
        if (tid == 64) red[3] = sv;
        __syncthreads();
        float inv = 1.0f / (red[2] + red[3]);
        if (tid < TE) sc[tid] = e2 * inv;
        __syncthreads();
        float acc = 0.f;
#pragma unroll 8
        for (int k = 0; k < 40; ++k) {
          int t = 2 * k + half;
          float g2v = (float)__builtin_bit_cast(_Float16, g2Lh[t * 264 + r2]);
          acc = fmaf(sc[t], g2v, acc);
        }
        acc += __shfl_xor(acc, 1);
        if (half == 0) gb[r2] = acc;
        __syncthreads();
      }
      if (tid < 64) {
        float gi = gb[tid] + a2p0 + x0;
        float gf = gb[64 + tid] + a2p1 + x1;
        float gG = gb[128 + tid] + a2p2 + x2;
        float go = gb[192 + tid] + a2p3 + x3;
        c2 = sigm(gf) * c2 + sigm(gi) * tanhf(gG);
        float h = sigm(go) * tanhf(c2);
        hnew[tid] = h;
      }
      if (tid < 32) {
        u32 pk = packh2(hnew[2 * tid], hnew[2 * tid + 1]);
        AT_STORE(&p.H2H[((size_t)U * 32 + b) * 128 + (q << 5) + tid], pk);
        if (U >= 81) {
          int rg = U - 81;
          u32 bk = packbf2(hnew[2 * tid], hnew[2 * tid + 1]);
          AT_STORE(&p.H2NB32[((size_t)rg * 32 + b) * 128 + (q << 5) + tid], bk);
        }
      }
      if (U >= 81) {
        asm volatile("s_waitcnt vmcnt(0)" ::: "memory");
        if (tid == 0) AT_ADD(&p.ctrs[C_RG + (U - 81)], 1);
      }
    }
    __syncthreads();
    do_logits(smem, p);
  }
  // ================= barrier over all 256 blocks =================
  asm volatile("s_waitcnt vmcnt(0)" ::: "memory");
  __syncthreads();
  if (tid == 0) {
    __hip_atomic_fetch_add(&p.ctrs[C_BAR], 1, __ATOMIC_RELEASE, __HIP_MEMORY_SCOPE_AGENT);
    int gd = 0;
    while (__hip_atomic_load(&p.ctrs[C_BAR], __ATOMIC_ACQUIRE, __HIP_MEMORY_SCOPE_AGENT) < 256 &&
           ++gd < GUARD)
      __builtin_amdgcn_s_sleep(2);
  }
  __syncthreads();
  // ================= final CE reduce: 4 rows per block =================
  {
    float* sm = (float*)smem;  // 512 floats
#pragma unroll
    for (int k = 0; k < 4; ++k) {
      int row = bid * 4 + k;
      if (row < 928) {
        const u32* pm = p.pmaxA + (size_t)row * 2000;
        const u32* psv = p.psumA + (size_t)row * 2000;
        float m = -INFINITY;
        for (int c = tid; c < 2000; c += 512) m = fmaxf(m, __uint_as_float(AT_LOAD(&pm[c])));
        sm[tid] = m;
        __syncthreads();
        for (int off = 256; off; off >>= 1) {
          if (tid < off) sm[tid] = fmaxf(sm[tid], sm[tid + off]);
          __syncthreads();
        }
        float M = sm[0];
        __syncthreads();
        float s = 0.f;
        for (int c = tid; c < 2000; c += 512)
          s += __uint_as_float(AT_LOAD(&psv[c])) * expf(__uint_as_float(AT_LOAD(&pm[c])) - M);
        sm[tid] = s;
        __syncthreads();
        for (int off = 256; off; off >>= 1) {
          if (tid < off) sm[tid] += sm[tid + off];
          __syncthreads();
        }
        if (tid == 0) {
          float tv = __uint_as_float(AT_LOAD(&p.tgtv[row]));
          atomicAdd(p.loss, (M + logf(sm[0]) - tv) * (1.0f / 1024.0f));
        }
        __syncthreads();
      }
    }
  }
  asm volatile("s_waitcnt vmcnt(0)" ::: "memory");
  if (tid == 0) {
    int old = __hip_atomic_fetch_add(&p.ctrs[C_WRT], 1, __ATOMIC_ACQ_REL, __HIP_MEMORY_SCOPE_AGENT);
    if (old == 255) p.out[0] = __uint_as_float(AT_LOAD((u32*)p.loss));
  }
}

// ---------------------------------------------------------------------------
extern "C" void kernel_launch(void* const* d_in, const int* in_sizes, int n_in,
                              void* d_out, int out_size, void* d_ws, size_t ws_size,
                              hipStream_t stream) {
  (void)in_sizes; (void)n_in; (void)out_size; (void)ws_size;
  const float* feat    = (const float*)d_in[0];
  const float* caption = (const float*)d_in[1];
  const float* onehot  = (const float*)d_in[2];
  const float* w_ih1   = (const float*)d_in[4];
  const float* w_hh1   = (const float*)d_in[5];
  const float* b_ih1   = (const float*)d_in[6];
  const float* b_hh1   = (const float*)d_in[7];
  const float* w_ih2   = (const float*)d_in[8];
  const float* w_hh2   = (const float*)d_in[9];
  const float* b_ih2   = (const float*)d_in[10];
  const float* b_hh2   = (const float*)d_in[11];
  const float* w_out   = (const float*)d_in[12];
  const float* b_out   = (const float*)d_in[13];

  char* p = (char*)d_ws;
  auto alloc = [&](size_t bytes) {
    char* r = p;
    p += (bytes + 255) & ~(size_t)255;
    return r;
  };
  float* bias1   = (float*)alloc(1024 * 4);
  float* bias2   = (float*)alloc(1024 * 4);
  u32*   H1H     = (u32*)alloc(110ull * 32 * 128 * 4);   // 1.8 MB
  u32*   H2H     = (u32*)alloc(110ull * 32 * 128 * 4);   // 1.8 MB
  u32*   A2P     = (u32*)alloc(110ull * 32 * 512 * 4);   // 7.2 MB
  u32*   H2NB32  = (u32*)alloc(29ull * 32 * 128 * 4);    // 475 KB
  u32*   pmaxA   = (u32*)alloc(928ull * 2000 * 4);       // 7.4 MB
  u32*   psumA   = (u32*)alloc(928ull * 2000 * 4);       // 7.4 MB
  u32*   tgtv    = (u32*)alloc(928 * 4);
  float* lossacc = (float*)alloc(256);
  int*   ctrs    = (int*)alloc(1024);
  int*   targets = (int*)alloc(29 * 32 * 4);
  u16*   w_ih1b  = (u16*)alloc(1024ull * 4096 * 2);      // 8.4 MB

  prep_kernel<<<1905, 256, 0, stream>>>(
      w_ih1, b_ih1, b_hh1, b_ih2, b_hh2,
      w_ih1b, bias1, bias2, H1H, H2H, A2P, lossacc, ctrs);

  RP rp;
  rp.feat = feat; rp.caption = caption; rp.onehot = onehot;
  rp.w_hh1 = w_hh1; rp.w_ih2 = w_ih2; rp.w_hh2 = w_hh2;
  rp.w_out = w_out; rp.b_out = b_out;
  rp.bias1 = bias1; rp.bias2 = bias2; rp.w_ih1b = w_ih1b;
  rp.H1H = H1H; rp.H2H = H2H; rp.A2P = A2P; rp.H2NB32 = H2NB32;
  rp.pmaxA = pmaxA; rp.psumA = psumA; rp.tgtv = tgtv;
  rp.loss = lossacc; rp.ctrs = ctrs; rp.targets = targets;
  rp.out = (float*)d_out;
  void* args[] = {&rp};
  hipLaunchCooperativeKernel((const void*)mega_kernel, dim3(256), dim3(512),
                             args, 0, stream);
}

// Round 14
// 742.395 us; speedup vs baseline: 1.0803x; 1.0803x over previous
//
#include <hip/hip_runtime.h>
#include <hip/hip_bf16.h>
#include <math.h>

// Problem dims
#define BB 32
#define TE 80
#define FEAT 4096
#define HH 256
#define W2V 256
#define TD 30
#define VV 32000
#define G4 1024   // 4*H

typedef unsigned short u16;
typedef unsigned int u32;
using f32x4 = __attribute__((ext_vector_type(4))) float;
using bf16x8 = __attribute__((ext_vector_type(8))) short;
using f16x2 = __attribute__((ext_vector_type(2))) _Float16;

#define SENT 0xFFFFFFFFu
#define GUARD (1 << 22)

__device__ __forceinline__ float sigm(float x) { return 1.0f / (1.0f + expf(-x)); }
__device__ __forceinline__ u16 f2bf(float f) {
  u32 u = __float_as_uint(f);
  u32 r = (u + 0x7FFFu + ((u >> 16) & 1u)) >> 16;
  return (u16)r;
}
__device__ __forceinline__ u32 packh2(float lo, float hi) {
  f16x2 v = {(_Float16)lo, (_Float16)hi};
  return __builtin_bit_cast(u32, v);
}

#define AT_LOAD(p)     __hip_atomic_load((p), __ATOMIC_RELAXED, __HIP_MEMORY_SCOPE_AGENT)
#define AT_STORE(p, v) __hip_atomic_store((p), (v), __ATOMIC_RELAXED, __HIP_MEMORY_SCOPE_AGENT)

__device__ __forceinline__ float fdot2h(f16x2 a, f16x2 b, float c) {
#if __has_builtin(__builtin_amdgcn_fdot2)
  return __builtin_amdgcn_fdot2(a, b, c, false);
#else
  return c + (float)a[0] * (float)b[0] + (float)a[1] * (float)b[1];
#endif
}

// ===========================================================================
// prep: argmax | w_ih1->bf16 | XW2 MFMA (inline cvt, +bias) | H sentinels |
// A2P sentinels | bias+misc.   3297 blocks.
// ===========================================================================
__global__ __launch_bounds__(256) void prep_kernel(
    const float* __restrict__ w_ih1, const float* __restrict__ w_ih2,
    const float* __restrict__ caption, const float* __restrict__ onehot,
    const float* __restrict__ b_ih1, const float* __restrict__ b_hh1,
    const float* __restrict__ b_ih2, const float* __restrict__ b_hh2,
    u16* __restrict__ w_ih1b, float* __restrict__ XW2,
    float* __restrict__ bias1, float* __restrict__ bias2,
    u32* __restrict__ H1H, u32* __restrict__ H2H, u32* __restrict__ A2P,
    float* __restrict__ loss, int* __restrict__ ctrs,
    int* __restrict__ targets) {
  __shared__ __align__(16) char psm[50688];
  int blk = blockIdx.x, tid = threadIdx.x;
  if (blk < 928) {
    int k = blk;  // (s-1)*32 + b
    int s = (k >> 5) + 1, b = k & 31;
    const float* row = &onehot[((size_t)b * TD + s) * VV];
    float bv = -INFINITY;
    int bi = 0x7fffffff;
    for (int v = tid; v < VV; v += 256) {
      float x = row[v];
      if (x > bv || (x == bv && v < bi)) { bv = x; bi = v; }
    }
    float* sv = (float*)psm;
    int* si = (int*)(psm + 1024);
    sv[tid] = bv; si[tid] = bi;
    __syncthreads();
    for (int off = 128; off; off >>= 1) {
      if (tid < off) {
        float ov = sv[tid + off]; int oi = si[tid + off];
        if (ov > sv[tid] || (ov == sv[tid] && oi < si[tid])) { sv[tid] = ov; si[tid] = oi; }
      }
      __syncthreads();
    }
    if (tid == 0) targets[k] = si[0];
  } else if (blk < 1952) {
    int i0 = (blk - 928) * 1024 + tid;
#pragma unroll
    for (int ii = 0; ii < 4; ++ii) {
      int i = i0 + ii * 256;
      float4 v = *(const float4*)&w_ih1[(size_t)i * 4];
      *(ushort4*)&w_ih1b[(size_t)i * 4] =
          make_ushort4(f2bf(v.x), f2bf(v.y), f2bf(v.z), f2bf(v.w));
    }
  } else if (blk < 2416) {
    // XW2[(t*32+b)][n] = bf16(caption[b][t][:]) . bf16(w_ih2[n][0:256]) + bias2[n]
    int k = blk - 1952, nb = k & 15, t = k >> 4;
    u16* As = (u16*)psm;                 // [32][264]
    u16* Bs = (u16*)(psm + 16896);       // [64][264]
    int nBase = nb * 64;
#pragma unroll
    for (int it = 0; it < 4; ++it) {
      int i = it * 256 + tid;
      int r = i >> 5, c8 = i & 31;
      const float* src = &caption[((size_t)r * TD + t) * 256 + c8 * 8];
      float4 v0 = *(const float4*)src;
      float4 v1 = *(const float4*)(src + 4);
      u16* dst = &As[r * 264 + c8 * 8];
      *(ushort4*)dst = make_ushort4(f2bf(v0.x), f2bf(v0.y), f2bf(v0.z), f2bf(v0.w));
      *(ushort4*)(dst + 4) = make_ushort4(f2bf(v1.x), f2bf(v1.y), f2bf(v1.z), f2bf(v1.w));
    }
#pragma unroll
    for (int it = 0; it < 8; ++it) {
      int i = it * 256 + tid;
      int r = i >> 5, c8 = i & 31;
      const float* src = &w_ih2[(size_t)(nBase + r) * 512 + c8 * 8];
      float4 v0 = *(const float4*)src;
      float4 v1 = *(const float4*)(src + 4);
      u16* dst = &Bs[r * 264 + c8 * 8];
      *(ushort4*)dst = make_ushort4(f2bf(v0.x), f2bf(v0.y), f2bf(v0.z), f2bf(v0.w));
      *(ushort4*)(dst + 4) = make_ushort4(f2bf(v1.x), f2bf(v1.y), f2bf(v1.z), f2bf(v1.w));
    }
    __syncthreads();
    int lane = tid & 63, w = tid >> 6;
    int lrow = lane & 15, lk = (lane >> 4) * 8;
    f32x4 acc[2];
    acc[0] = (f32x4){0.f, 0.f, 0.f, 0.f};
    acc[1] = (f32x4){0.f, 0.f, 0.f, 0.f};
#pragma unroll
    for (int ks = 0; ks < 8; ++ks) {
      bf16x8 bfr = *(const bf16x8*)&Bs[(w * 16 + lrow) * 264 + ks * 32 + lk];
#pragma unroll
      for (int m = 0; m < 2; ++m) {
        bf16x8 af = *(const bf16x8*)&As[(m * 16 + lrow) * 264 + ks * 32 + lk];
        acc[m] = __builtin_amdgcn_mfma_f32_16x16x32_bf16(af, bfr, acc[m], 0, 0, 0);
      }
    }
    int col = nBase + w * 16 + (lane & 15);
    float bv = b_ih2[col] + b_hh2[col];
    int orow = (lane >> 4) * 4;
#pragma unroll
    for (int m = 0; m < 2; ++m)
#pragma unroll
      for (int qq = 0; qq < 4; ++qq) {
        int bb = m * 16 + orow + qq;
        XW2[((size_t)t * 32 + bb) * G4 + col] = acc[m][qq] + bv;
      }
  } else if (blk < 2856) {
    int i = (blk - 2416) * 256 + tid;  // uint4 idx < 112640
    uint4 z = {0u, 0u, 0u, 0u};
    uint4 s = {SENT, SENT, SENT, SENT};
    uint4 v = (i < 1024) ? z : s;      // slot T=0 = packed f16 zeros
    ((uint4*)H1H)[i] = v;
    ((uint4*)H2H)[i] = v;
  } else if (blk < 3296) {
    int i0 = (blk - 2856) * 1024 + tid;  // uint4 idx < 450560
    uint4 s = {SENT, SENT, SENT, SENT};
#pragma unroll
    for (int ii = 0; ii < 4; ++ii) ((uint4*)A2P)[i0 + ii * 256] = s;
  } else {
    for (int i = tid; i < 1024; i += 256) {
      bias1[i] = b_ih1[i] + b_hh1[i];
      bias2[i] = b_ih2[i] + b_hh2[i];
    }
    if (tid < 256) ctrs[tid] = 0;
    if (tid == 0) *loss = 0.0f;
  }
}

// ===========================================================================
// gemm_x1: X1[r][n] = feat[r][:] . w_ih1b[n][:] + bias1[n]; A f32 inline cvt.
// ===========================================================================
#define GBM 128
#define GBN 128
#define GBK 64
#define LDSTR 72

__global__ __launch_bounds__(256) void gemm_x1_kernel(
    const float* __restrict__ A, const u16* __restrict__ Bw,
    const float* __restrict__ bias, float* __restrict__ C) {
  __shared__ __align__(16) u16 As[GBM * LDSTR];
  __shared__ __align__(16) u16 Bs[GBN * LDSTR];
  int tid = threadIdx.x;
  int rBase = (blockIdx.x >> 3) * GBM;
  int nBase = (blockIdx.x & 7) * GBN;
  int lane = tid & 63, w = tid >> 6;
  int wrow = (w >> 1) * 64, wcol = (w & 1) * 64;
  int lrow = lane & 15, lk = (lane >> 4) * 8;

  f32x4 acc[4][4];
#pragma unroll
  for (int m = 0; m < 4; ++m)
#pragma unroll
    for (int n = 0; n < 4; ++n) acc[m][n] = (f32x4){0.f, 0.f, 0.f, 0.f};

  for (int k0 = 0; k0 < FEAT; k0 += GBK) {
#pragma unroll
    for (int i = 0; i < 8; ++i) {
      int f = i * 256 + tid;
      int r = f >> 4, c = (f & 15) << 2;
      float4 v = *(const float4*)&A[(size_t)(rBase + r) * FEAT + k0 + c];
      *(ushort4*)&As[r * LDSTR + c] =
          make_ushort4(f2bf(v.x), f2bf(v.y), f2bf(v.z), f2bf(v.w));
    }
#pragma unroll
    for (int i = 0; i < 4; ++i) {
      int f = i * 256 + tid;
      int r = f >> 3, c8 = f & 7;
      *(uint4*)&Bs[r * LDSTR + c8 * 8] =
          *(const uint4*)&Bw[(size_t)(nBase + r) * FEAT + k0 + c8 * 8];
    }
    __syncthreads();
#pragma unroll
    for (int s2 = 0; s2 < 2; ++s2) {
      bf16x8 af[4], bfr[4];
#pragma unroll
      for (int m = 0; m < 4; ++m)
        af[m] = *(const bf16x8*)&As[(wrow + m * 16 + lrow) * LDSTR + s2 * 32 + lk];
#pragma unroll
      for (int n = 0; n < 4; ++n)
        bfr[n] = *(const bf16x8*)&Bs[(wcol + n * 16 + lrow) * LDSTR + s2 * 32 + lk];
#pragma unroll
      for (int m = 0; m < 4; ++m)
#pragma unroll
        for (int n = 0; n < 4; ++n)
          acc[m][n] = __builtin_amdgcn_mfma_f32_16x16x32_bf16(
              af[m], bfr[n], acc[m][n], 0, 0, 0);
    }
    __syncthreads();
  }
  int orow = (lane >> 4) * 4;
  int ocol = lane & 15;
#pragma unroll
  for (int m = 0; m < 4; ++m)
#pragma unroll
    for (int n = 0; n < 4; ++n) {
      int cidx = nBase + wcol + n * 16 + ocol;
      float bv = bias[cidx];
#pragma unroll
      for (int q = 0; q < 4; ++q) {
        int r = rBase + wrow + m * 16 + orow + q;
        C[(size_t)r * G4 + cidx] = acc[m][n][q] + bv;
      }
    }
}

// ===========================================================================
// Persistent recurrent kernel (round-11-proven structure; packed A2P).
// 256 blocks x 512 threads. L1 [0,128): h1 chain (wA) + a2p (wB), publish
// packed pairs. L2B [128,256): h2 chain (wC only), encL history, attention.
// ===========================================================================
struct RP {
  const float *X1, *XW2, *bias1, *bias2;
  const float *w_hh1, *w_ih2, *w_hh2;
  u32* H1H;     // [110][32][128] packed f16x2 of h1[T]
  u32* H2H;     // [110][32][128] packed f16x2 of h2[U]
  u32* A2P;     // [110][32][512] packed f16x2 pairs of a2 rows
  u16* H2NB;    // [29][32][256] bf16 decoder h2n
};

__global__ __launch_bounds__(512, 1) void recurrent_kernel(RP p) {
  __shared__ float encL[TE][257];             // 82 KB (L2B only)
  __shared__ __align__(16) f16x2 hS[128];
  __shared__ float tmp2[256];
  __shared__ float gb[256];
  __shared__ float a2pS[256];
  __shared__ float hnew[64];
  __shared__ float sc[80];
  __shared__ float red[4];
  int bid = blockIdx.x, tid = threadIdx.x;
  bool isL1 = bid < 128;
  int lb = isL1 ? bid : bid - 128;
  int b = lb >> 2, q = lb & 3;
  int r2 = tid >> 1, half = tid & 1;
  int g = r2 >> 6, jj = r2 & 63;
  int grow = (g << 8) + (q << 6) + jj;
  int jf = (q << 6) + tid;  // valid for tid<64

  if (isL1) {
    f16x2 wA[64], wB[64];
    {
      const float4* sA = (const float4*)(p.w_hh1 + (size_t)grow * 256 + half * 128);
      const float4* sB = (const float4*)(p.w_ih2 + (size_t)grow * 512 + 256 + half * 128);
#pragma unroll
      for (int k = 0; k < 32; ++k) {
        float4 v = sA[k];
        wA[k * 2 + 0] = f16x2{(_Float16)v.x, (_Float16)v.y};
        wA[k * 2 + 1] = f16x2{(_Float16)v.z, (_Float16)v.w};
        float4 u = sB[k];
        wB[k * 2 + 0] = f16x2{(_Float16)u.x, (_Float16)u.y};
        wB[k * 2 + 1] = f16x2{(_Float16)u.z, (_Float16)u.w};
      }
    }
    float c1 = 0.f;
    float b1v0 = 0, b1v1 = 0, b1v2 = 0, b1v3 = 0;
    if (tid < 64) {
      b1v0 = p.bias1[jf]; b1v1 = p.bias1[256 + jf];
      b1v2 = p.bias1[512 + jf]; b1v3 = p.bias1[768 + jf];
    }
    for (int T = 0; T <= 109; ++T) {
      float x0 = b1v0, x1 = b1v1, x2 = b1v2, x3 = b1v3;
      if (tid < 64 && T < TE) {
        const float* xb = &p.X1[((size_t)b * TE + T) * G4 + jf];
        x0 = xb[0]; x1 = xb[256]; x2 = xb[512]; x3 = xb[768];
      }
      if (tid < 128) {
        const u32* src = &p.H1H[((size_t)T * 32 + b) * 128 + tid];
        u32 v = AT_LOAD(src);
        int gd = 0;
        while (v == SENT && ++gd < GUARD) {
          __builtin_amdgcn_s_sleep(1);
          v = AT_LOAD(src);
        }
        hS[tid] = __builtin_bit_cast(f16x2, v);
      }
      __syncthreads();  // S1
      float a1 = 0.f, a2 = 0.f;
      {
        const uint4* hv = ((const uint4*)hS) + half * 16;
#pragma unroll
        for (int k = 0; k < 16; ++k) {
          uint4 uu = hv[k];
          f16x2 e0 = __builtin_bit_cast(f16x2, uu.x), e1 = __builtin_bit_cast(f16x2, uu.y);
          f16x2 e2 = __builtin_bit_cast(f16x2, uu.z), e3 = __builtin_bit_cast(f16x2, uu.w);
          a1 = fdot2h(e0, wA[k * 4 + 0], a1);
          a2 = fdot2h(e0, wB[k * 4 + 0], a2);
          a1 = fdot2h(e1, wA[k * 4 + 1], a1);
          a2 = fdot2h(e1, wB[k * 4 + 1], a2);
          a1 = fdot2h(e2, wA[k * 4 + 2], a1);
          a2 = fdot2h(e2, wB[k * 4 + 2], a2);
          a1 = fdot2h(e3, wA[k * 4 + 3], a1);
          a2 = fdot2h(e3, wB[k * 4 + 3], a2);
        }
      }
      a1 += __shfl_xor(a1, 1);
      a2 += __shfl_xor(a2, 1);
      float a2o = __shfl_xor(a2, 2);  // partner row's a2
      if (half == 0) gb[r2] = a1;
      if ((tid & 3) == 0 && T >= 1) {
        int pr = tid >> 2;  // pair 0..127
        int gp = pr >> 5, wp = pr & 31;
        AT_STORE(&p.A2P[((size_t)T * 32 + b) * 512 + (gp << 7) + (q << 5) + wp],
                 packh2(a2, a2o));
      }
      __syncthreads();  // S2
      if (T <= 108) {
        if (tid < 64) {
          float gi = gb[tid] + x0;
          float gf = gb[64 + tid] + x1;
          float gG = gb[128 + tid] + x2;
          float go = gb[192 + tid] + x3;
          c1 = sigm(gf) * c1 + sigm(gi) * tanhf(gG);
          hnew[tid] = sigm(go) * tanhf(c1);
        }
        if (tid < 32) {  // same wave as hnew writers
          u32 pk = packh2(hnew[2 * tid], hnew[2 * tid + 1]);
          AT_STORE(&p.H1H[((size_t)(T + 1) * 32 + b) * 128 + (q << 5) + tid], pk);
        }
      }
    }
  } else {
    f16x2 wC[64];
    {
      const float4* sC = (const float4*)(p.w_hh2 + (size_t)grow * 256 + half * 128);
#pragma unroll
      for (int k = 0; k < 32; ++k) {
        float4 u = sC[k];
        wC[k * 2 + 0] = f16x2{(_Float16)u.x, (_Float16)u.y};
        wC[k * 2 + 1] = f16x2{(_Float16)u.z, (_Float16)u.w};
      }
    }
    float c2 = 0.f;
    float b2v0 = 0, b2v1 = 0, b2v2 = 0, b2v3 = 0;
    if (tid < 64) {
      b2v0 = p.bias2[jf]; b2v1 = p.bias2[256 + jf];
      b2v2 = p.bias2[512 + jf]; b2v3 = p.bias2[768 + jf];
    }
    for (int U = 1; U <= 109; ++U) {
      float x0 = b2v0, x1 = b2v1, x2 = b2v2, x3 = b2v3;
      if (tid < 64 && U >= 81) {
        const float* xb = &p.XW2[((size_t)(U - 81) * 32 + b) * G4 + jf];
        x0 = xb[0]; x1 = xb[256]; x2 = xb[512]; x3 = xb[768];  // bias folded
      }
      // concurrent polls: h2[U-1] (pure spin) and packed a2p[U]
      if (tid < 128) {
        const u32* src = &p.H2H[((size_t)(U - 1) * 32 + b) * 128 + tid];
        u32 v = AT_LOAD(src);
        int gd = 0;
        while (v == SENT && ++gd < (GUARD << 2)) v = AT_LOAD(src);
        f16x2 hp = __builtin_bit_cast(f16x2, v);
        hS[tid] = hp;
        tmp2[2 * tid] = (float)hp[0];
        tmp2[2 * tid + 1] = (float)hp[1];
      } else if (tid < 256) {
        int rr = tid - 128;
        int gp = rr >> 5, wp = rr & 31;
        const u32* src = &p.A2P[((size_t)U * 32 + b) * 512 + (gp << 7) + (q << 5) + wp];
        u32 v = AT_LOAD(src);
        int gd = 0;
        while (v == SENT && ++gd < GUARD) {
          __builtin_amdgcn_s_sleep(1);
          v = AT_LOAD(src);
        }
        f16x2 pr = __builtin_bit_cast(f16x2, v);
        a2pS[gp * 64 + 2 * wp] = (float)pr[0];
        a2pS[gp * 64 + 2 * wp + 1] = (float)pr[1];
      }
      __syncthreads();  // S1
      float a2p0 = 0, a2p1 = 0, a2p2 = 0, a2p3 = 0;
      if (tid < 64) {
        a2p0 = a2pS[tid]; a2p1 = a2pS[64 + tid];
        a2p2 = a2pS[128 + tid]; a2p3 = a2pS[192 + tid];
      }
      if (U <= 81) {
        if (U >= 2 && tid < 256) encL[U - 2][tid] = tmp2[tid];
      } else {
        // attention: q-vec = tmp2 (h2n[s-1]); parallel softmax; ctx -> hS
        float a = 0.f;
        if (tid < TE) {
          const float* e = &encL[tid][0];
#pragma unroll 8
          for (int k2 = 0; k2 < 256; ++k2) a += e[k2] * tmp2[k2];
        }
        float av = (tid < TE) ? a : -INFINITY;
#pragma unroll
        for (int d = 32; d; d >>= 1) av = fmaxf(av, __shfl_xor(av, d));
        if (tid == 0) red[0] = av;
        if (tid == 64) red[1] = av;
        __syncthreads();
        float m = fmaxf(red[0], red[1]);
        float e2 = (tid < TE) ? expf(a - m) : 0.f;
        float sv = e2;
#pragma unroll
        for (int d = 32; d; d >>= 1) sv += __shfl_xor(sv, d);
        if (tid == 0) red[2] = sv;
        if (tid == 64) red[3] = sv;
        __syncthreads();
        float inv = 1.0f / (red[2] + red[3]);
        if (tid < TE) sc[tid] = e2 * inv;
        __syncthreads();
        if (tid < 256) {
          float acc = 0.f;
          for (int t2 = 0; t2 < TE; ++t2) acc += sc[t2] * encL[t2][tid];
          tmp2[tid] = acc;
        }
        __syncthreads();
        if (tid < 128)
          hS[tid] = f16x2{(_Float16)tmp2[2 * tid], (_Float16)tmp2[2 * tid + 1]};
      }
      __syncthreads();
      float a2 = 0.f;
      {
        const uint4* hv = ((const uint4*)hS) + half * 16;
#pragma unroll
        for (int k = 0; k < 16; ++k) {
          uint4 uu = hv[k];
          a2 = fdot2h(__builtin_bit_cast(f16x2, uu.x), wC[k * 4 + 0], a2);
          a2 = fdot2h(__builtin_bit_cast(f16x2, uu.y), wC[k * 4 + 1], a2);
          a2 = fdot2h(__builtin_bit_cast(f16x2, uu.z), wC[k * 4 + 2], a2);
          a2 = fdot2h(__builtin_bit_cast(f16x2, uu.w), wC[k * 4 + 3], a2);
        }
      }
      a2 += __shfl_xor(a2, 1);
      if (half == 0) gb[r2] = a2;
      __syncthreads();
      if (tid < 64) {
        float gi = gb[tid] + a2p0 + x0;
        float gf = gb[64 + tid] + a2p1 + x1;
        float gG = gb[128 + tid] + a2p2 + x2;
        float go = gb[192 + tid] + a2p3 + x3;
        c2 = sigm(gf) * c2 + sigm(gi) * tanhf(gG);
        float h = sigm(go) * tanhf(c2);
        hnew[tid] = h;
        if (U >= 81)
          p.H2NB[((size_t)(U - 81) * 32 + b) * 256 + jf] = f2bf(h);
      }
      if (tid < 32) {  // same wave as hnew writers
        u32 pk = packh2(hnew[2 * tid], hnew[2 * tid + 1]);
        AT_STORE(&p.H2H[((size_t)U * 32 + b) * 128 + (q << 5) + tid], pk);
      }
    }
  }
}

// ===========================================================================
// Fused logits + CE partials + final reduce (250 co-resident blocks).
// ===========================================================================
__global__ __launch_bounds__(256, 1) void logits_final_kernel(
    const u16* __restrict__ H2NB, const float* __restrict__ w_out,
    const float* __restrict__ b_out, const int* __restrict__ targets,
    u32* __restrict__ pmaxA, u32* __restrict__ psumA, u32* __restrict__ tgtv,
    float* __restrict__ loss, int* __restrict__ ctrs, float* __restrict__ out) {
  __shared__ __align__(16) u16 bS[32768];
  __shared__ __align__(16) u16 aS[32 * 264];
  __shared__ int tS[32];
  __shared__ float sm[256];
  int tid = threadIdx.x, bid = blockIdx.x;
#pragma unroll
  for (int it = 0; it < 16; ++it) {
    int id = it * 256 + tid;
    int nt = id >> 9, rr = (id >> 5) & 15, kg = id & 31;
    int n = bid * 128 + nt * 16 + rr;
    const float* src = &w_out[(size_t)n * 256 + kg * 8];
    float4 v0 = *(const float4*)src;
    float4 v1 = *(const float4*)(src + 4);
    u16* dst = &bS[(size_t)((nt * 32 + kg) * 16 + rr) * 8];
    *(ushort4*)dst = make_ushort4(f2bf(v0.x), f2bf(v0.y), f2bf(v0.z), f2bf(v0.w));
    *(ushort4*)(dst + 4) = make_ushort4(f2bf(v1.x), f2bf(v1.y), f2bf(v1.z), f2bf(v1.w));
  }
  int wid = tid >> 6, lane = tid & 63, lcol = lane & 15, lk = lane >> 4;
  float bo[2];
#pragma unroll
  for (int n = 0; n < 2; ++n) bo[n] = b_out[(bid * 8 + wid * 2 + n) * 16 + lcol];

  for (int rg = 0; rg < 29; ++rg) {
    __syncthreads();
    for (int i = tid; i < 1024; i += 256) {
      int r = i >> 5, c8 = i & 31;
      *(uint4*)&aS[r * 264 + c8 * 8] =
          *(const uint4*)&H2NB[(size_t)rg * 8192 + r * 256 + c8 * 8];
    }
    if (tid < 32) tS[tid] = targets[rg * 32 + tid];
    __syncthreads();
    f32x4 acc[2][2];
#pragma unroll
    for (int m = 0; m < 2; ++m)
#pragma unroll
      for (int n = 0; n < 2; ++n) acc[m][n] = (f32x4){0.f, 0.f, 0.f, 0.f};
#pragma unroll
    for (int ks = 0; ks < 8; ++ks) {
      bf16x8 a0 = *(const bf16x8*)&aS[lcol * 264 + ks * 32 + lk * 8];
      bf16x8 a1 = *(const bf16x8*)&aS[(16 + lcol) * 264 + ks * 32 + lk * 8];
      bf16x8 b0 = *(const bf16x8*)&bS[(wid * 2) * 4096 + ((ks * 4 + lk) * 16 + lcol) * 8];
      bf16x8 b1 = *(const bf16x8*)&bS[(wid * 2 + 1) * 4096 + ((ks * 4 + lk) * 16 + lcol) * 8];
      acc[0][0] = __builtin_amdgcn_mfma_f32_16x16x32_bf16(a0, b0, acc[0][0], 0, 0, 0);
      acc[0][1] = __builtin_amdgcn_mfma_f32_16x16x32_bf16(a0, b1, acc[0][1], 0, 0, 0);
      acc[1][0] = __builtin_amdgcn_mfma_f32_16x16x32_bf16(a1, b0, acc[1][0], 0, 0, 0);
      acc[1][1] = __builtin_amdgcn_mfma_f32_16x16x32_bf16(a1, b1, acc[1][1], 0, 0, 0);
    }
    int nbase = (bid * 8 + wid * 2) * 16 + lcol;
#pragma unroll
    for (int m = 0; m < 2; ++m) {
      float pm[4], psv[4];
#pragma unroll
      for (int qq = 0; qq < 4; ++qq) {
        float v0 = acc[m][0][qq] + bo[0];
        float v1 = acc[m][1][qq] + bo[1];
        int r = m * 16 + lk * 4 + qq;
        int tg = tS[r];
        if (tg == nbase) AT_STORE(&tgtv[rg * 32 + r], __float_as_uint(v0));
        if (tg == nbase + 16) AT_STORE(&tgtv[rg * 32 + r], __float_as_uint(v1));
        float mx = fmaxf(v0, v1);
#pragma unroll
        for (int d = 1; d < 16; d <<= 1) mx = fmaxf(mx, __shfl_xor(mx, d));
        float e = expf(v0 - mx) + expf(v1 - mx);
#pragma unroll
        for (int d = 1; d < 16; d <<= 1) e += __shfl_xor(e, d);
        pm[qq] = mx;
        psv[qq] = e;
      }
      if (lcol == 0) {
        int chunk = bid * 4 + wid;
#pragma unroll
        for (int qq = 0; qq < 4; ++qq) {
          int r2 = rg * 32 + m * 16 + lk * 4 + qq;
          AT_STORE(&pmaxA[(size_t)r2 * 1000 + chunk], __float_as_uint(pm[qq]));
          AT_STORE(&psumA[(size_t)r2 * 1000 + chunk], __float_as_uint(psv[qq]));
        }
      }
    }
  }
  asm volatile("s_waitcnt vmcnt(0)" ::: "memory");
  __syncthreads();
  if (tid == 0) {
    __hip_atomic_fetch_add(&ctrs[0], 1, __ATOMIC_RELEASE, __HIP_MEMORY_SCOPE_AGENT);
    int gd = 0;
    while (__hip_atomic_load(&ctrs[0], __ATOMIC_ACQUIRE, __HIP_MEMORY_SCOPE_AGENT) < 250 &&
           ++gd < GUARD)
      __builtin_amdgcn_s_sleep(2);
  }
  __syncthreads();
#pragma unroll
  for (int k = 0; k < 4; ++k) {
    int row = bid * 4 + k;
    if (row < 928) {
      const u32* pm = pmaxA + (size_t)row * 1000;
      const u32* psv = psumA + (size_t)row * 1000;
      float m = -INFINITY;
      for (int c = tid; c < 1000; c += 256) m = fmaxf(m, __uint_as_float(AT_LOAD(&pm[c])));
      sm[tid] = m;
      __syncthreads();
      for (int off = 128; off; off >>= 1) {
        if (tid < off) sm[tid] = fmaxf(sm[tid], sm[tid + off]);
        __syncthreads();
      }
      float M = sm[0];
      __syncthreads();
      float s = 0.f;
      for (int c = tid; c < 1000; c += 256)
        s += __uint_as_float(AT_LOAD(&psv[c])) * expf(__uint_as_float(AT_LOAD(&pm[c])) - M);
      sm[tid] = s;
      __syncthreads();
      for (int off = 128; off; off >>= 1) {
        if (tid < off) sm[tid] += sm[tid + off];
        __syncthreads();
      }
      if (tid == 0) {
        float tv = __uint_as_float(AT_LOAD(&tgtv[row]));
        atomicAdd(loss, (M + logf(sm[0]) - tv) * (1.0f / 1024.0f));
      }
      __syncthreads();
    }
  }
  asm volatile("s_waitcnt vmcnt(0)" ::: "memory");
  if (tid == 0) {
    int old = __hip_atomic_fetch_add(&ctrs[32], 1, __ATOMIC_ACQ_REL, __HIP_MEMORY_SCOPE_AGENT);
    if (old == 249) out[0] = __uint_as_float(AT_LOAD((u32*)loss));
  }
}

// ---------------------------------------------------------------------------
extern "C" void kernel_launch(void* const* d_in, const int* in_sizes, int n_in,
                              void* d_out, int out_size, void* d_ws, size_t ws_size,
                              hipStream_t stream) {
  (void)in_sizes; (void)n_in; (void)out_size; (void)ws_size;
  const float* feat    = (const float*)d_in[0];
  const float* caption = (const float*)d_in[1];
  const float* onehot  = (const float*)d_in[2];
  const float* w_ih1   = (const float*)d_in[4];
  const float* w_hh1   = (const float*)d_in[5];
  const float* b_ih1   = (const float*)d_in[6];
  const float* b_hh1   = (const float*)d_in[7];
  const float* w_ih2   = (const float*)d_in[8];
  const float* w_hh2   = (const float*)d_in[9];
  const float* b_ih2   = (const float*)d_in[10];
  const float* b_hh2   = (const float*)d_in[11];
  const float* w_out   = (const float*)d_in[12];
  const float* b_out   = (const float*)d_in[13];

  char* p = (char*)d_ws;
  auto alloc = [&](size_t bytes) {
    char* r = p;
    p += (bytes + 255) & ~(size_t)255;
    return r;
  };
  float* X1      = (float*)alloc(2560ull * 1024 * 4);    // 10.5 MB
  float* XW2     = (float*)alloc(29ull * 32 * 1024 * 4); // 3.8 MB
  float* bias1   = (float*)alloc(1024 * 4);
  float* bias2   = (float*)alloc(1024 * 4);
  u32*   H1H     = (u32*)alloc(110ull * 32 * 128 * 4);   // 1.8 MB
  u32*   H2H     = (u32*)alloc(110ull * 32 * 128 * 4);   // 1.8 MB
  u32*   A2P     = (u32*)alloc(110ull * 32 * 512 * 4);   // 7.2 MB
  u16*   H2NB    = (u16*)alloc(29ull * 8192 * 2);
  u32*   pmaxA   = (u32*)alloc(928ull * 1000 * 4);
  u32*   psumA   = (u32*)alloc(928ull * 1000 * 4);
  u32*   tgtv    = (u32*)alloc(928 * 4);
  float* lossacc = (float*)alloc(256);
  int*   ctrs    = (int*)alloc(1024);
  int*   targets = (int*)alloc(29 * 32 * 4);
  u16*   w_ih1b  = (u16*)alloc(1024ull * 4096 * 2);      // 8.4 MB

  prep_kernel<<<3297, 256, 0, stream>>>(
      w_ih1, w_ih2, caption, onehot,
      b_ih1, b_hh1, b_ih2, b_hh2,
      w_ih1b, XW2, bias1, bias2, H1H, H2H, A2P, lossacc, ctrs, targets);

  gemm_x1_kernel<<<160, 256, 0, stream>>>(feat, w_ih1b, bias1, X1);

  RP rp;
  rp.X1 = X1; rp.XW2 = XW2; rp.bias1 = bias1; rp.bias2 = bias2;
  rp.w_hh1 = w_hh1; rp.w_ih2 = w_ih2; rp.w_hh2 = w_hh2;
  rp.H1H = H1H; rp.H2H = H2H; rp.A2P = A2P; rp.H2NB = H2NB;
  void* args[] = {&rp};
  hipLaunchCooperativeKernel((const void*)recurrent_kernel, dim3(256), dim3(512),
                             args, 0, stream);

  logits_final_kernel<<<250, 256, 0, stream>>>(H2NB, w_out, b_out, targets,
                                               pmaxA, psumA, tgtv, lossacc, ctrs,
                                               (float*)d_out);
}